// Round 1
// baseline (667.761 us; speedup 1.0000x reference)
//
#include <hip/hip_runtime.h>
#include <hip/hip_bf16.h>

// Problem: N=8192 nodes, DIN=DOUT=256.
// out0 = relu( diag(d) (A+I) diag(d) (x @ W^T) ),  d_i = rsqrt(1 + #(A_ij>eps))
// out1 = A (verbatim copy; harness poisons d_out each call)
constexpr int NN = 8192;
constexpr int DD = 256;

typedef __bf16 bf16_t;
typedef __bf16 bf16x8 __attribute__((ext_vector_type(8)));
typedef float  floatx4  __attribute__((ext_vector_type(4)));
typedef float  floatx16 __attribute__((ext_vector_type(16)));

#define GLOBAL_AS __attribute__((address_space(1)))
#define LDS_AS    __attribute__((address_space(3)))

// ---------------------------------------------------------------------------
// K1: per-row degree + verbatim copy of A into out1. Pure streaming.
// Nontemporal stores: don't let the copy evict A from L3 (k3 re-reads A).
// ---------------------------------------------------------------------------
__global__ __launch_bounds__(256) void k1_deg_copy(const float* __restrict__ A,
                                                   float* __restrict__ Aout,
                                                   float* __restrict__ dvec) {
    const int row = blockIdx.x;
    const int t = threadIdx.x;
    const floatx4* __restrict__ src = (const floatx4*)(A + (size_t)row * NN);
    floatx4* __restrict__ dst = (floatx4*)(Aout + (size_t)row * NN);
    int cnt = 0;
#pragma unroll
    for (int i = 0; i < 8; ++i) {
        floatx4 v = src[t + 256 * i];
        __builtin_nontemporal_store(v, &dst[t + 256 * i]);
        cnt += (v.x > 1e-15f) + (v.y > 1e-15f) + (v.z > 1e-15f) + (v.w > 1e-15f);
    }
#pragma unroll
    for (int off = 32; off > 0; off >>= 1) cnt += __shfl_down(cnt, off, 64);
    __shared__ int wsum[4];
    if ((t & 63) == 0) wsum[t >> 6] = cnt;
    __syncthreads();
    if (t == 0) {
        int total = wsum[0] + wsum[1] + wsum[2] + wsum[3];
        dvec[row] = rsqrtf(1.0f + (float)total);
    }
}

// load 8 consecutive fp32 and convert to a bf16x8 MFMA fragment
__device__ inline bf16x8 load_cvt8(const float* __restrict__ p) {
    floatx4 v0 = *(const floatx4*)p;
    floatx4 v1 = *(const floatx4*)(p + 4);
    bf16x8 r;
    r[0] = (bf16_t)v0.x; r[1] = (bf16_t)v0.y; r[2] = (bf16_t)v0.z; r[3] = (bf16_t)v0.w;
    r[4] = (bf16_t)v1.x; r[5] = (bf16_t)v1.y; r[6] = (bf16_t)v1.z; r[7] = (bf16_t)v1.w;
    return r;
}

// ---------------------------------------------------------------------------
// K2: H^T = W @ x^T via 16x16x32 bf16 MFMA.  M=256 (n), N=8192 (j), K=256.
// gT[n][j] = d_j * h[j][n]  (bf16, k-contiguous for K3 B-frags)
// out[j][n] = d_j^2 * h[j][n] (the A+I self-term = K3's accumulator init).
// Grid 512: block = 64 n x 64 j (2 blocks/CU for latency hiding).
// ---------------------------------------------------------------------------
__global__ __launch_bounds__(256) void k2_h_gt(const float* __restrict__ x,
                                               const float* __restrict__ W,
                                               const float* __restrict__ dvec,
                                               bf16_t* __restrict__ gT,
                                               float* __restrict__ out) {
    const int t = threadIdx.x;
    const int l = t & 63, w = t >> 6;
    const int lm = l & 15, q = l >> 4;
    const int nb = blockIdx.x & 3, jb = blockIdx.x >> 2;
    const int n0 = nb * 64 + w * 16;
    const int j0 = jb * 64;

    floatx4 acc[4] = {};
#pragma unroll
    for (int kt = 0; kt < 256; kt += 32) {
        const int k = kt + q * 8;
        bf16x8 a = load_cvt8(W + (size_t)(n0 + lm) * DD + k);
#pragma unroll
        for (int jt = 0; jt < 4; ++jt) {
            bf16x8 b = load_cvt8(x + (size_t)(j0 + jt * 16 + lm) * DD + k);
            acc[jt] = __builtin_amdgcn_mfma_f32_16x16x32_bf16(a, b, acc[jt], 0, 0, 0);
        }
    }
    // C/D layout: col(j) = lane&15, row(n) = (lane>>4)*4 + reg   [m89-verified]
#pragma unroll
    for (int jt = 0; jt < 4; ++jt) {
        const int j = j0 + jt * 16 + lm;
        const float dj = dvec[j];
#pragma unroll
        for (int r = 0; r < 4; ++r) {
            const int n = n0 + q * 4 + r;
            const float hv = acc[jt][r];
            gT[(size_t)n * NN + j] = (bf16_t)(dj * hv);
            out[(size_t)j * DD + n] = dj * dj * hv;
        }
    }
}

// ---------------------------------------------------------------------------
// K3: out[m,n] = relu( d_m * sum_j A[m,j]*gT[n,j] + init[m,n] )   (init = d^2 h
// from K2, already in out).  Grid 256 = one block per 32-row tile, FULL K=8192:
// no K-split, no atomics, relu fused (K4 deleted).  4 waves n-split (wave w:
// n = w*64..+63 as two 32x32 subtiles), MFMA 32x32x16, acc = 2x f32x16/wave.
// A staged fp32 in LDS via async global_load_lds, K-chunk=128 (16KB), double-
// buffered.  XOR swizzle (phys unit = log unit ^ row) applied on the GLOBAL
// source (gl_lds dest must be linear [m104/m173]); ds_reads un-swizzle.
// B-frags (16B) direct from gT: 4MB, L2/L3-resident; ~42 B/cyc/CU at the
// HBM-bound pace of the A stream.
// ---------------------------------------------------------------------------
__global__ __launch_bounds__(256) void k3_gemm(const float* __restrict__ A,
                                               const bf16_t* __restrict__ gT,
                                               const float* __restrict__ dvec,
                                               float* __restrict__ out) {
    __shared__ __align__(16) float As[2][32 * 128];  // 2 x 16KB fp32, swizzled
    __shared__ float sd[32];
    const int t = threadIdx.x;
    const int l = t & 63, w = t >> 6;
    const int ln = l & 31, half = l >> 5;
    const int m0 = blockIdx.x * 32;

    if (t < 32) sd[t] = dvec[m0 + t];

    // stage one 32x128 fp32 chunk: 1024 16B-units, 4 gl_lds per thread.
    // phys unit p = j*256 + t: row r = p>>5, u_phys = p&31, u_log = u_phys ^ r.
    auto stage = [&](int kc, float* buf) {
#pragma unroll
        for (int j = 0; j < 4; ++j) {
            const int p = j * 256 + t;
            const int r = p >> 5;
            const int ulog = (p & 31) ^ r;
            const float* src = A + (size_t)(m0 + r) * NN + kc + ulog * 4;
            float* ldsb = buf + (size_t)(j * 256 + w * 64) * 4;  // wave-uniform base
            __builtin_amdgcn_global_load_lds((const GLOBAL_AS void*)src,
                                             (LDS_AS void*)ldsb, 16, 0, 0);
        }
    };
    // A-frag for row ln, K-step s: logical 16B-units u0,u0+1 (u0 = s*4 + half*2)
    auto read_a = [&](const float* buf, int s) -> bf16x8 {
        const int u0 = s * 4 + half * 2;
        const floatx4 f0 = *(const floatx4*)(buf + (size_t)(ln * 32 + (u0 ^ ln)) * 4);
        const floatx4 f1 = *(const floatx4*)(buf + (size_t)(ln * 32 + ((u0 + 1) ^ ln)) * 4);
        bf16x8 r;
        r[0] = (bf16_t)f0.x; r[1] = (bf16_t)f0.y; r[2] = (bf16_t)f0.z; r[3] = (bf16_t)f0.w;
        r[4] = (bf16_t)f1.x; r[5] = (bf16_t)f1.y; r[6] = (bf16_t)f1.z; r[7] = (bf16_t)f1.w;
        return r;
    };

    floatx16 acc0 = {}, acc1 = {};
    // B-frag base: lane holds gT[n = w*64 + ln][k = half*8 ..], 16B loads
    const bf16_t* gb = gT + (size_t)(w * 64 + ln) * NN + half * 8;

    stage(0, As[0]);
    __syncthreads();  // vmcnt drain: chunk 0 resident
    for (int c = 0; c < 64; ++c) {
        if (c + 1 < 64) stage((c + 1) * 128, As[(c + 1) & 1]);  // async, depth-1
        const float* buf = As[c & 1];
#pragma unroll
        for (int s = 0; s < 8; ++s) {
            const size_t kg = (size_t)(c * 128 + s * 16);
            bf16x8 a = read_a(buf, s);
            bf16x8 b0 = *(const bf16x8*)(gb + kg);
            bf16x8 b1 = *(const bf16x8*)(gb + (size_t)32 * NN + kg);
            acc0 = __builtin_amdgcn_mfma_f32_32x32x16_bf16(a, b0, acc0, 0, 0, 0);
            acc1 = __builtin_amdgcn_mfma_f32_32x32x16_bf16(a, b1, acc1, 0, 0, 0);
        }
        __syncthreads();  // drains stage(c+1); LDS reads of buf done in all waves
    }

    // C/D 32x32 [m74/m101]: col = lane&31, row = (reg&3) + 8*(reg>>2) + 4*(lane>>5)
#pragma unroll
    for (int g = 0; g < 4; ++g)
#pragma unroll
        for (int r4 = 0; r4 < 4; ++r4) {
            const int reg = g * 4 + r4;
            const int ml = r4 + 8 * g + 4 * half;
            const float dm = sd[ml];
            float* p0 = out + (size_t)(m0 + ml) * DD + w * 64 + ln;
            const float v0 = dm * acc0[reg] + p0[0];    // + init (d^2 h self-term)
            const float v1 = dm * acc1[reg] + p0[32];
            p0[0]  = fmaxf(v0, 0.f);
            p0[32] = fmaxf(v1, 0.f);
        }
}

extern "C" void kernel_launch(void* const* d_in, const int* in_sizes, int n_in,
                              void* d_out, int out_size, void* d_ws, size_t ws_size,
                              hipStream_t stream) {
    const float* x = (const float*)d_in[0];  // [8192,256]
    const float* A = (const float*)d_in[1];  // [8192,8192]
    const float* W = (const float*)d_in[2];  // [256,256]
    float* out0 = (float*)d_out;                     // [8192,256]
    float* out1 = out0 + (size_t)NN * DD;            // A copy [8192,8192]
    float* dvec = (float*)d_ws;                      // 32KB
    bf16_t* gT = (bf16_t*)((char*)d_ws + 32768);     // 4MB

    k1_deg_copy<<<NN, 256, 0, stream>>>(A, out1, dvec);
    k2_h_gt<<<512, 256, 0, stream>>>(x, W, dvec, gT, out0);
    k3_gemm<<<256, 256, 0, stream>>>(A, gT, dvec, out0);
}